// Round 2
// baseline (931.174 us; speedup 1.0000x reference)
//
#include <hip/hip_runtime.h>
#include <math.h>

// EMRouting: B=8,H=12,W=12,K=3,CIN=16,COUT=32,P=16 -> 1152 positions x 144 votes
#define NPOS 1152
#define NN   144
#define COUT 32
#define PP   16
#define EPSF 1e-7f
#define LOG2PI 1.8378770664093453f

#define MU_OFF   0
#define A_OFF    589824            // 1152*32*16
#define SIG_OFF  626688            // + 1152*32

// DPP helper: butterfly partner move on the VALU pipe (no LDS traffic).
template<int CTRL>
__device__ __forceinline__ float dppf(float x) {
    return __int_as_float(__builtin_amdgcn_update_dpp(
        0, __float_as_int(x), CTRL, 0xf, 0xf, true));
}

// Reduce over the 32-lane half-wave (verified R1: butterfly via quad_perm,
// row_half_mirror, row_mirror; final 16-cross via one shuffle).
__device__ __forceinline__ float redmax32(float m) {
    m = fmaxf(m, dppf<0xB1>(m));      // quad_perm [1,0,3,2]
    m = fmaxf(m, dppf<0x4E>(m));      // quad_perm [2,3,0,1]
    m = fmaxf(m, dppf<0x141>(m));     // row_half_mirror
    m = fmaxf(m, dppf<0x140>(m));     // row_mirror
    m = fmaxf(m, __shfl_xor(m, 16, 64));
    return m;
}
__device__ __forceinline__ float redsum32(float s) {
    s += dppf<0xB1>(s);
    s += dppf<0x4E>(s);
    s += dppf<0x141>(s);
    s += dppf<0x140>(s);
    s += __shfl_xor(s, 16, 64);
    return s;
}

// Fold the two n-subsets (xor 32) and write this wave's partials to red[b].
__device__ __forceinline__ void fold_write(float S0, float (&S1)[PP], float (&S2)[PP],
                                           float (*rbw)[36], int tid, int c)
{
    S0 += __shfl_xor(S0, 32, 64);
    #pragma unroll
    for (int p = 0; p < PP; ++p) {
        S1[p] += __shfl_xor(S1[p], 32, 64);
        S2[p] += __shfl_xor(S2[p], 32, 64);
    }
    float* rb = rbw[c];
    if ((tid & 32) == 0) {
        #pragma unroll
        for (int q = 0; q < 4; ++q)
            ((float4*)rb)[q] = make_float4(S1[4*q], S1[4*q+1], S1[4*q+2], S1[4*q+3]);
        rb[32] = S0;
    } else {
        #pragma unroll
        for (int q = 0; q < 4; ++q)
            ((float4*)rb)[4 + q] = make_float4(S2[4*q], S2[4*q+1], S2[4*q+2], S2[4*q+3]);
    }
}

// Finalize: every thread redundantly computes its own cout lane c.
// On !last: sets E-step registers (A, B2, cl2) for the next iteration.
// On last: wave 0 writes mu/sigma/a_out straight from registers.
__device__ __forceinline__ void finalize_iter(
    const float (&rb)[4][32][36], int c, int tid, int pos, float lam,
    float Bu_c, float Ba_c, bool last,
    float (&A_r)[PP], float (&B2_r)[PP], float& cl2, float* __restrict__ out)
{
    float s1[PP], s2[PP], d0 = 0.f;
    #pragma unroll
    for (int p = 0; p < PP; ++p) { s1[p] = 0.f; s2[p] = 0.f; }
    #pragma unroll
    for (int w = 0; w < 4; ++w) {
        const float* rr = &rb[w][c][0];
        #pragma unroll
        for (int q = 0; q < 4; ++q) {
            const float4 x = ((const float4*)rr)[q];
            s1[4*q] += x.x; s1[4*q+1] += x.y; s1[4*q+2] += x.z; s1[4*q+3] += x.w;
        }
        #pragma unroll
        for (int q = 0; q < 4; ++q) {
            const float4 x = ((const float4*)rr)[4 + q];
            s2[4*q] += x.x; s2[4*q+1] += x.y; s2[4*q+2] += x.z; s2[4*q+3] += x.w;
        }
        d0 += rr[32];
    }

    const float inv = __fdividef(1.f, d0 + EPSF);
    float mu[PP], sg[PP], sumlog = 0.f;
    #pragma unroll
    for (int p = 0; p < PP; ++p) {
        const float m_ = s1[p] * inv;
        float g = (s2[p] - 2.f * m_ * s1[p] + m_ * m_ * d0) * inv;
        g = fmaxf(g, 1e-30f);               // guard cancellation -> log NaN
        mu[p] = m_;
        sg[p] = g;
        sumlog += __logf(g);
    }
    // sum_p cost_h = d0*(P*Beta_u + 0.5*sumlog); x = Lam*(Beta_a - that)
    const float xs  = lam * (Ba_c - d0 * (16.f * Bu_c + 0.5f * sumlog));
    const float nn2 = redsum32(xs * xs);    // l2 over cout, wave-parallel
    const float y   = xs / fmaxf(sqrtf(nn2), 1e-12f);
    const float ao  = 1.f / (1.f + __expf(-y));

    if (!last) {
        // log_p1 = -0.5*(P*log(2pi) + sumlog) + EPS
        const float cl = __logf(ao) - 0.5f * (16.f * LOG2PI + sumlog) + EPSF;
        float Cacc = 0.f;
        #pragma unroll
        for (int p = 0; p < PP; ++p) {
            const float wp = __fdividef(1.f, 2.f * sg[p] + EPSF);
            A_r[p]  = wp;
            B2_r[p] = 2.f * wp * mu[p];
            Cacc = fmaf(wp * mu[p], mu[p], Cacc);
        }
        cl2 = cl - Cacc;
    } else if (tid < 32) {
        float4* mo = (float4*)(out + MU_OFF  + (size_t)pos * (COUT * PP) + c * PP);
        float4* so = (float4*)(out + SIG_OFF + (size_t)pos * (COUT * PP) + c * PP);
        #pragma unroll
        for (int q = 0; q < 4; ++q) {
            mo[q] = make_float4(mu[4*q], mu[4*q+1], mu[4*q+2], mu[4*q+3]);
            so[q] = make_float4(sg[4*q], sg[4*q+1], sg[4*q+2], sg[4*q+3]);
        }
        out[A_OFF + pos * COUT + c] = ao;
    }
}

// Load vote (j) of this thread's slot sequence into rotating buffer slot jj.
#define LOADV(jj, j) do { const float4* p_ = vq + (size_t)(j) * 1024; \
    buf[jj][0] = p_[0]; buf[jj][1] = p_[1]; buf[jj][2] = p_[2]; buf[jj][3] = p_[3]; } while (0)

#define EXTRACT(vv, jj) const float vv[PP] = { \
    buf[jj][0].x, buf[jj][0].y, buf[jj][0].z, buf[jj][0].w, \
    buf[jj][1].x, buf[jj][1].y, buf[jj][1].z, buf[jj][1].w, \
    buf[jj][2].x, buf[jj][2].y, buf[jj][2].z, buf[jj][2].w, \
    buf[jj][3].x, buf[jj][3].y, buf[jj][3].z, buf[jj][3].w }

// Block = 256 threads = 4 waves. cout = tid&31, n-slot = tid>>5 (8 slots,
// n = slot + 8*j, j=0..17). Depth-8 rotating register prefetch, j-loops
// fully unrolled so every buffer index is compile-time and the scheduler
// keeps ~32 b128 loads in flight per wave. One barrier per EM iteration.
__global__ void __launch_bounds__(256, 2)
em_routing_kernel(const float* __restrict__ V,
                  const float* __restrict__ a,
                  const float* __restrict__ Bu,
                  const float* __restrict__ Ba,
                  const float* __restrict__ Rin,
                  float* __restrict__ out)
{
    const int pos  = blockIdx.x;
    const int tid  = threadIdx.x;
    const int c    = tid & 31;   // cout lane
    const int slot = tid >> 5;   // 0..7
    const int wave = tid >> 6;   // 0..3

    const float* Vp = V + (size_t)pos * (NN * COUT * PP);
    const float* Rp = Rin + (size_t)pos * (NN * COUT);

    __shared__ float a_s[NN];
    // [buf][wave][c][ S1[0..15] | S2[16..31] | S0[32] ], stride 36 floats.
    __shared__ __align__(16) float red[2][4][32][36];

    for (int i = tid; i < NN; i += 256) a_s[i] = a[pos * NN + i];
    __syncthreads();

    const float Bu_c = Bu[c];
    const float Ba_c = Ba[c];

    const float4* vq = (const float4*)(Vp + slot * (COUT * PP) + c * PP);
    const float*  rq = Rp + slot * COUT + c;

    float A_r[PP], B2_r[PP];
    float cl2 = 0.f;

    float4 buf[8][4];

    const float L0 = 0.01f * (1.f - 0.95f);
    const float L1 = 0.01f * (1.f - 0.95f * 0.95f);
    const float L2 = 0.01f * (1.f - 0.95f * 0.95f * 0.95f);

    // ---------------- iteration 0: pure streaming M-step ----------------
    {
        float S0 = 0.f, S1[PP], S2[PP];
        #pragma unroll
        for (int p = 0; p < PP; ++p) { S1[p] = 0.f; S2[p] = 0.f; }

        float rbuf[8];
        #pragma unroll
        for (int jj = 0; jj < 8; ++jj) { LOADV(jj, jj); rbuf[jj] = rq[jj * 256]; }

        #pragma unroll
        for (int j = 0; j < 18; ++j) {
            EXTRACT(v, j & 7);
            const float rc = rbuf[j & 7];
            if (j < 10) { LOADV(j & 7, j + 8); rbuf[j & 7] = rq[(j + 8) * 256]; }
            const float av = a_s[slot + (j << 3)];
            const float Rw = rc * av;
            S0 += Rw;
            #pragma unroll
            for (int p = 0; p < PP; ++p) {
                const float t = Rw * v[p];
                S1[p] += t;
                S2[p] = fmaf(t, v[p], S2[p]);
            }
        }
        // issue iteration 1's burst now — it flies under the finalize
        #pragma unroll
        for (int jj = 0; jj < 8; ++jj) LOADV(jj, jj);

        fold_write(S0, S1, S2, red[0][wave], tid, c);
        __syncthreads();   // the ONLY barrier in the iteration
        finalize_iter(red[0], c, tid, pos, L0, Bu_c, Ba_c, false, A_r, B2_r, cl2, out);
    }

    // ---------------- iterations 1,2: E-step + M-step ----------------
    #pragma unroll 1
    for (int it = 1; it < 3; ++it) {
        float S0 = 0.f, S1[PP], S2[PP];
        #pragma unroll
        for (int p = 0; p < PP; ++p) { S1[p] = 0.f; S2[p] = 0.f; }

        #pragma unroll
        for (int j = 0; j < 18; ++j) {
            EXTRACT(v, j & 7);
            if (j < 10) LOADV(j & 7, j + 8);
            const float av = a_s[slot + (j << 3)];
            // logit = cl - sum_p wp*(v-mu)^2 = cl2 + sum_p (B2 - A*v)*v
            float logit = cl2;
            #pragma unroll
            for (int p = 0; p < PP; ++p) {
                const float t = fmaf(-A_r[p], v[p], B2_r[p]);
                logit = fmaf(t, v[p], logit);
            }
            const float m = redmax32(logit);
            const float e = __expf(logit - m);
            const float s = redsum32(e);
            const float Rw = __fdividef(e, s) * av;
            S0 += Rw;
            #pragma unroll
            for (int p = 0; p < PP; ++p) {
                const float t = Rw * v[p];
                S1[p] += t;
                S2[p] = fmaf(t, v[p], S2[p]);
            }
        }
        if (it < 2) {   // issue iteration 2's burst before the barrier
            #pragma unroll
            for (int jj = 0; jj < 8; ++jj) LOADV(jj, jj);
        }

        fold_write(S0, S1, S2, red[it & 1][wave], tid, c);
        __syncthreads();
        finalize_iter(red[it & 1], c, tid, pos, (it == 1) ? L1 : L2,
                      Bu_c, Ba_c, (it == 2), A_r, B2_r, cl2, out);
    }
}

extern "C" void kernel_launch(void* const* d_in, const int* in_sizes, int n_in,
                              void* d_out, int out_size, void* d_ws, size_t ws_size,
                              hipStream_t stream) {
    const float* V  = (const float*)d_in[0];
    const float* a  = (const float*)d_in[1];
    const float* Bu = (const float*)d_in[2];
    const float* Ba = (const float*)d_in[3];
    const float* R  = (const float*)d_in[4];
    float* out = (float*)d_out;
    em_routing_kernel<<<NPOS, 256, 0, stream>>>(V, a, Bu, Ba, R, out);
}